// Round 8
// baseline (4383.773 us; speedup 1.0000x reference)
//
#include <hip/hip_runtime.h>
#include <math.h>
#include <stdint.h>

#define SLEN 1024

__device__ __forceinline__ float sigf(float x) { return 1.0f / (1.0f + __expf(-x)); }

__device__ __forceinline__ uint32_t aldu(const uint32_t* p) {
  return __hip_atomic_load(p, __ATOMIC_RELAXED, __HIP_MEMORY_SCOPE_AGENT);
}
__device__ __forceinline__ void astu(uint32_t* p, uint32_t v) {
  __hip_atomic_store(p, v, __ATOMIC_RELAXED, __HIP_MEMORY_SCOPE_AGENT);
}
__device__ __forceinline__ float aldf(const float* p) {
  return __hip_atomic_load(p, __ATOMIC_RELAXED, __HIP_MEMORY_SCOPE_AGENT);
}
__device__ __forceinline__ void astf(float* p, float v) {
  __hip_atomic_store(p, v, __ATOMIC_RELAXED, __HIP_MEMORY_SCOPE_AGENT);
}
__device__ __forceinline__ bool sentu(uint32_t v) { return v == 0xFFFFFFFFu; }
__device__ __forceinline__ bool sentf(float f) { return __float_as_uint(f) == 0xFFFFFFFFu; }
// bf16-pair pack/unpack. Sentinel 0xFFFFFFFF = two bf16 NaNs: unreachable from
// finite h. Each h-chunk is ONE store transaction -> per-dword atomic visibility.
__device__ __forceinline__ float blo(uint32_t d) { return __uint_as_float(d << 16); }
__device__ __forceinline__ float bhi(uint32_t d) { return __uint_as_float(d & 0xFFFF0000u); }
__device__ __forceinline__ uint32_t bpack(float lo, float hi) {
  uint32_t a = __float_as_uint(lo), b = __float_as_uint(hi);
  a = (a + 0x7FFFu + ((a >> 16) & 1u)) >> 16;          // RNE
  b = (b + 0x7FFFu + ((b >> 16) & 1u)) & 0xFFFF0000u;  // RNE, kept high
  return b | a;
}

// In-loop register pin (R5-proven for <=64 floats/thread).
__device__ __forceinline__ void pin4(float4& v) {
  asm volatile("" : "+v"(v.x), "+v"(v.y), "+v"(v.z), "+v"(v.w));
}
#define DOT4(acc, wv, iv)                                                  \
  acc += (wv).x * (iv).x + (wv).y * (iv).y + (wv).z * (iv).z + (wv).w * (iv).w

// ---------------------------------------------------------------------------
// xg0_k: xg0[t][u][0..3] = Wih0 rows . emb[tok_t] + bih0 + bhh0 (t-parallel)
// ---------------------------------------------------------------------------
__global__ __launch_bounds__(512, 2) void xg0_k(const int* __restrict__ tokens,
                                                const float* __restrict__ emb,
                                                const float* __restrict__ Wih0,
                                                const float* __restrict__ bih0,
                                                const float* __restrict__ bhh0,
                                                float* __restrict__ xg0) {
  const int tid = threadIdx.x, c = tid & 63, w = tid >> 6;
  const int ublk = blockIdx.x & 127;
  const int tph  = blockIdx.x >> 7;
  const int u = ublk * 8 + w;
  const float4* emb4 = (const float4*)emb;
  float4 wr[4][2];
  float bb[4];
  #pragma unroll
  for (int g = 0; g < 4; ++g) {
    const size_t row = (size_t)g * 1024 + u;
    const float4* w4 = (const float4*)(Wih0 + row * 512);
    wr[g][0] = w4[2 * c];
    wr[g][1] = w4[2 * c + 1];
    bb[g] = bih0[row] + bhh0[row];
  }
  float4* xg4 = (float4*)xg0;
  for (int t = tph; t < SLEN; t += 8) {
    const int tok = tokens[t * 64 + 63];
    const float4 e0 = emb4[(size_t)tok * 128 + 2 * c];
    const float4 e1 = emb4[(size_t)tok * 128 + 2 * c + 1];
    float a[4] = {0.f, 0.f, 0.f, 0.f};
    #pragma unroll
    for (int g = 0; g < 4; ++g) { DOT4(a[g], wr[g][0], e0); DOT4(a[g], wr[g][1], e1); }
    #pragma unroll
    for (int off = 32; off > 0; off >>= 1)
      #pragma unroll
      for (int g = 0; g < 4; ++g) a[g] += __shfl_xor(a[g], off);
    if (c == 0)
      xg4[(size_t)t * 1024 + u] =
          make_float4(a[0] + bb[0], a[1] + bb[1], a[2] + bb[2], a[3] + bb[3]);
  }
}

// ---------------------------------------------------------------------------
// L0: 64 blocks x 16 units. Wave w owns unit u0+w in regs (64f, RA-safe) and
// unit u0+8+w via LDS weights (128KB). Wave 0 polls the packed h0[t-1]
// (8 dwords/lane), unpacks into in_f, 1 barrier releases compute.
// h store: tid<8 pack -> one 32B transaction covering 16 units.
// ---------------------------------------------------------------------------
__device__ void l0_role(int blk, char* blob, const float* __restrict__ Whh,
                        const float* __restrict__ xg0, uint32_t* __restrict__ houtp) {
  float4* wlds4 = (float4*)blob;               // 8192 float4 = 128 KB
  float*  in_f  = (float*)(blob + 131072);     // 1024 f32
  float*  hg    = in_f + 1024;                 // 16 f32
  const int tid = threadIdx.x, c = tid & 63, w = tid >> 6;
  const int u0 = blk * 16;

  for (int k = tid; k < 8192; k += 512) {      // LDS units u0+8+ww
    const int wg = k >> 8, rem = k & 255, s = rem >> 6, cc = rem & 63;
    const int ww = wg >> 2, g = wg & 3;
    wlds4[k] = ((const float4*)Whh)[((size_t)g * 1024 + (u0 + 8 + ww)) * 256 + s * 64 + cc];
  }
  float4 wreg[4][4];                           // reg unit u0+w
  #pragma unroll
  for (int g = 0; g < 4; ++g) {
    const float4* r4 = (const float4*)Whh + ((size_t)g * 1024 + (u0 + w)) * 256;
    #pragma unroll
    for (int s = 0; s < 4; ++s) wreg[g][s] = r4[s * 64 + c];
  }
  __syncthreads();

  const float4* xg4 = (const float4*)xg0;
  float cst = 0.f;

  for (int t = 0; t < SLEN; ++t) {
    #pragma unroll
    for (int g = 0; g < 4; ++g) {
      #pragma unroll
      for (int s = 0; s < 4; ++s) pin4(wreg[g][s]);
    }

    if (w == 0) {                              // single-wave integrated poll+stage
      if (t > 0) {
        const uint32_t* hp = houtp + (size_t)(t - 1) * 512;
        uint32_t hv[8];
        for (;;) {
          bool ok = true;
          #pragma unroll
          for (int i = 0; i < 8; ++i) hv[i] = aldu(hp + i * 64 + c);
          #pragma unroll
          for (int i = 0; i < 8; ++i) ok &= !sentu(hv[i]);
          if (ok) break;
          __builtin_amdgcn_s_sleep(2);
        }
        #pragma unroll
        for (int i = 0; i < 8; ++i)
          ((float2*)in_f)[i * 64 + c] = make_float2(blo(hv[i]), bhi(hv[i]));
      } else {
        #pragma unroll
        for (int i = 0; i < 8; ++i)
          ((float2*)in_f)[i * 64 + c] = make_float2(0.f, 0.f);
      }
    }
    __syncthreads();                           // barrier 1: input staged

    float a[8];
    #pragma unroll
    for (int r = 0; r < 8; ++r) a[r] = 0.f;
    const float4* iv4 = (const float4*)in_f;
    #pragma unroll
    for (int s = 0; s < 4; ++s) {
      const float4 iv = iv4[s * 64 + c];
      #pragma unroll
      for (int g = 0; g < 4; ++g) {
        DOT4(a[g], wreg[g][s], iv);
        const float4 wv = wlds4[(w * 4 + g) * 256 + s * 64 + c];
        DOT4(a[4 + g], wv, iv);
      }
    }
    #pragma unroll
    for (int off = 32; off > 0; off >>= 1)
      #pragma unroll
      for (int r = 0; r < 8; ++r) a[r] += __shfl_xor(a[r], off);

    if (c < 2) {
      const int lu = (c == 0) ? w : 8 + w;
      const int base = c * 4;
      const float4 xgv = xg4[(size_t)t * 1024 + u0 + lu];
      const float I = sigf(a[base + 0] + xgv.x);
      const float F = sigf(a[base + 1] + xgv.y);
      const float G = tanhf(a[base + 2] + xgv.z);
      const float O = sigf(a[base + 3] + xgv.w);
      cst = F * cst + I * G;
      hg[lu] = O * tanhf(cst);
    }
    __syncthreads();                           // barrier 2: hg ready
    if (tid < 8)
      astu(houtp + (size_t)t * 512 + blk * 8 + tid, bpack(hg[2 * tid], hg[2 * tid + 1]));
  }
}

// ---------------------------------------------------------------------------
// Generic role (L1/L2): wave owns 1 unit (8 units/block); RSLOTS weight slots
// in regs, SLOTS-RSLOTS in LDS. Wave 0 polls packed input + own h[t-1].
// PACK_OUT: h published packed-bf16 (4 dwords, one 16B txn) or f32 (8 dwords,
// one 32B txn). Store coverage is ALWAYS the block's 8 units (R7 deadlock fix).
// ---------------------------------------------------------------------------
template<int HOUT, int EIN, int RSLOTS, bool PACK_OUT>
__device__ void lstm_role(int ublk, char* blob,
                          const float* __restrict__ Wih, const float* __restrict__ Whh,
                          const float* __restrict__ bih, const float* __restrict__ bhh,
                          const uint32_t* __restrict__ inp,
                          uint32_t* __restrict__ houtp, float* __restrict__ houtf) {
  constexpr int C = EIN + HOUT;
  constexpr int SLOTS = C / 256;
  constexpr int LSLOTS = SLOTS - RSLOTS;
  constexpr int XQ = EIN / 4;
  constexpr int AND = EIN / 128;               // packed input dwords per lane
  constexpr int BND = PACK_OUT ? (HOUT / 128) : (HOUT / 64);  // own-h words/lane

  float4* wlds4 = (float4*)blob;
  float*  in_f  = (float*)(blob + (size_t)LSLOTS * 32 * 64 * 16);
  float*  hg    = in_f + C;

  const int tid = threadIdx.x, c = tid & 63, w = tid >> 6;
  const int u0 = ublk * 8, u = u0 + w;

  for (int k = tid; k < LSLOTS * 32 * 64; k += 512) {
    const int cc = k & 63, rr = k >> 6, r = rr & 31, sl = rr >> 5;
    const int g = r & 3, wu = r >> 2;
    const size_t grow = (size_t)g * HOUT + (size_t)(u0 + wu);
    const float4* wih4 = (const float4*)(Wih + grow * EIN);
    const float4* whh4 = (const float4*)(Whh + grow * HOUT);
    const int c4 = (RSLOTS + sl) * 64 + cc;
    wlds4[k] = (c4 < XQ) ? wih4[c4] : whh4[c4 - XQ];
  }
  float4 wreg[4][RSLOTS];
  #pragma unroll
  for (int g = 0; g < 4; ++g) {
    const size_t grow = (size_t)g * HOUT + (size_t)u;
    const float4* wih4 = (const float4*)(Wih + grow * EIN);
    const float4* whh4 = (const float4*)(Whh + grow * HOUT);
    #pragma unroll
    for (int s = 0; s < RSLOTS; ++s) {
      const int c4 = s * 64 + c;
      wreg[g][s] = (c4 < XQ) ? wih4[c4] : whh4[c4 - XQ];
    }
  }
  float bg[4] = {0.f, 0.f, 0.f, 0.f};
  float cst = 0.f;
  if (c == 0) {
    #pragma unroll
    for (int g = 0; g < 4; ++g) bg[g] = bih[g * HOUT + u] + bhh[g * HOUT + u];
  }
  __syncthreads();

  for (int t = 0; t < SLEN; ++t) {
    #pragma unroll
    for (int g = 0; g < 4; ++g) {
      #pragma unroll
      for (int s = 0; s < RSLOTS; ++s) pin4(wreg[g][s]);
    }

    if (w == 0) {                              // single-wave integrated poll+stage
      uint32_t av[AND];
      float bf[BND];
      uint32_t bu[BND];
      for (;;) {
        bool ok = true;
        #pragma unroll
        for (int i = 0; i < AND; ++i) av[i] = aldu(inp + (size_t)t * (EIN / 2) + i * 64 + c);
        if (t > 0) {
          if constexpr (PACK_OUT) {
            #pragma unroll
            for (int i = 0; i < BND; ++i)
              bu[i] = aldu(houtp + (size_t)(t - 1) * (HOUT / 2) + i * 64 + c);
            #pragma unroll
            for (int i = 0; i < BND; ++i) ok &= !sentu(bu[i]);
          } else {
            #pragma unroll
            for (int i = 0; i < BND; ++i)
              bf[i] = aldf(houtf + (size_t)(t - 1) * HOUT + i * 64 + c);
            #pragma unroll
            for (int i = 0; i < BND; ++i) ok &= !sentf(bf[i]);
          }
        }
        #pragma unroll
        for (int i = 0; i < AND; ++i) ok &= !sentu(av[i]);
        if (ok) break;
        __builtin_amdgcn_s_sleep(2);
      }
      #pragma unroll
      for (int i = 0; i < AND; ++i)
        ((float2*)in_f)[i * 64 + c] = make_float2(blo(av[i]), bhi(av[i]));
      if (t > 0) {
        if constexpr (PACK_OUT) {
          #pragma unroll
          for (int i = 0; i < BND; ++i)
            ((float2*)(in_f + EIN))[i * 64 + c] = make_float2(blo(bu[i]), bhi(bu[i]));
        } else {
          #pragma unroll
          for (int i = 0; i < BND; ++i) in_f[EIN + i * 64 + c] = bf[i];
        }
      } else {
        if constexpr (PACK_OUT) {
          #pragma unroll
          for (int i = 0; i < BND; ++i)
            ((float2*)(in_f + EIN))[i * 64 + c] = make_float2(0.f, 0.f);
        } else {
          #pragma unroll
          for (int i = 0; i < BND; ++i) in_f[EIN + i * 64 + c] = 0.f;
        }
      }
    }
    __syncthreads();                           // barrier 1

    float a[4] = {0.f, 0.f, 0.f, 0.f};
    const float4* iv4 = (const float4*)in_f;
    #pragma unroll
    for (int s = 0; s < RSLOTS; ++s) {
      const float4 iv = iv4[s * 64 + c];
      #pragma unroll
      for (int g = 0; g < 4; ++g) DOT4(a[g], wreg[g][s], iv);
    }
    #pragma unroll
    for (int sl = 0; sl < LSLOTS; ++sl) {
      const float4 iv = iv4[(RSLOTS + sl) * 64 + c];
      #pragma unroll
      for (int g = 0; g < 4; ++g) {
        const float4 wv = wlds4[((sl * 32) + (w * 4 + g)) * 64 + c];
        DOT4(a[g], wv, iv);
      }
    }
    #pragma unroll
    for (int off = 32; off > 0; off >>= 1)
      #pragma unroll
      for (int g = 0; g < 4; ++g) a[g] += __shfl_xor(a[g], off);

    if (c == 0) {
      const float I = sigf(a[0] + bg[0]);
      const float F = sigf(a[1] + bg[1]);
      const float G = tanhf(a[2] + bg[2]);
      const float O = sigf(a[3] + bg[3]);
      cst = F * cst + I * G;
      hg[w] = O * tanhf(cst);
    }
    __syncthreads();                           // barrier 2
    if constexpr (PACK_OUT) {                  // 8 units -> 4 dwords, 16B txn
      if (tid < 4)
        astu(houtp + (size_t)t * (HOUT / 2) + ublk * 4 + tid,
             bpack(hg[2 * tid], hg[2 * tid + 1]));
    } else {                                   // 8 units -> 8 f32, 32B txn
      if (tid < 8)
        astf(houtf + (size_t)t * HOUT + ublk * 8 + tid, hg[tid]);
    }
  }
}

// out[t,:] = h2f[t,:] @ Wlin.T + blin; 8 blocks, t strided by 8
__device__ void final_role(int fb, char* blob, const float* __restrict__ h2f,
                           const float* __restrict__ Wlin, const float* __restrict__ blin,
                           float* __restrict__ out) {
  float* red = (float*)blob;                   // 28 f32
  const int tid = threadIdx.x;
  float wl[7];
  #pragma unroll
  for (int o = 0; o < 7; ++o) wl[o] = 0.f;
  if (tid < 256) {
    #pragma unroll
    for (int o = 0; o < 7; ++o) wl[o] = Wlin[o * 256 + tid];
  }
  for (int t = fb; t < SLEN; t += 8) {
    float h = 0.f;
    if (tid < 256) {
      h = aldf(h2f + (size_t)t * 256 + tid);
      while (sentf(h)) {
        __builtin_amdgcn_s_sleep(2);
        h = aldf(h2f + (size_t)t * 256 + tid);
      }
    }
    float p[7];
    #pragma unroll
    for (int o = 0; o < 7; ++o) p[o] = h * wl[o];
    #pragma unroll
    for (int off = 32; off > 0; off >>= 1) {
      #pragma unroll
      for (int o = 0; o < 7; ++o) p[o] += __shfl_xor(p[o], off);
    }
    const int w = tid >> 6;
    if (w < 4 && (tid & 63) == 0) {
      #pragma unroll
      for (int o = 0; o < 7; ++o) red[w * 7 + o] = p[o];
    }
    __syncthreads();
    if (tid == 0) {
      #pragma unroll
      for (int o = 0; o < 7; ++o)
        out[t * 7 + o] = red[0 + o] + red[7 + o] + red[14 + o] + red[21 + o] + blin[o];
    }
    __syncthreads();
  }
}

// L0 is the max LDS user: 131072 + 4096 + 64 = 135232 B.
#define PIPE_DYN_LDS 135232

__global__ __attribute__((amdgpu_flat_work_group_size(512, 512),
                          amdgpu_waves_per_eu(2, 2))) void pipe_k(
    const float* __restrict__ xg0, const float* __restrict__ Whh0,
    const float* __restrict__ Wih1, const float* __restrict__ Whh1,
    const float* __restrict__ bih1, const float* __restrict__ bhh1,
    const float* __restrict__ Wih2, const float* __restrict__ Whh2,
    const float* __restrict__ bih2, const float* __restrict__ bhh2,
    const float* __restrict__ Wlin, const float* __restrict__ blin,
    uint32_t* __restrict__ h0p, uint32_t* __restrict__ h1p, float* __restrict__ h2f,
    float* __restrict__ out) {
  extern __shared__ __align__(16) char blob[];
  const int b = blockIdx.x;
  if (b < 64) {
    l0_role(b, blob, Whh0, xg0, h0p);
  } else if (b < 128) {
    lstm_role<512, 1024, 3, true>(b - 64, blob, Wih1, Whh1, bih1, bhh1, h0p, h1p, nullptr);
  } else if (b < 160) {
    lstm_role<256, 512, 3, false>(b - 128, blob, Wih2, Whh2, bih2, bhh2, h1p, nullptr, h2f);
  } else {
    final_role(b - 160, blob, h2f, Wlin, blin, out);
  }
}

extern "C" void kernel_launch(void* const* d_in, const int* in_sizes, int n_in,
                              void* d_out, int out_size, void* d_ws, size_t ws_size,
                              hipStream_t stream) {
  const int*   tokens = (const int*)  d_in[0];
  const float* emb  = (const float*)d_in[1];
  const float* Wih0 = (const float*)d_in[2];
  const float* Whh0 = (const float*)d_in[3];
  const float* bih0 = (const float*)d_in[4];
  const float* bhh0 = (const float*)d_in[5];
  const float* Wih1 = (const float*)d_in[6];
  const float* Whh1 = (const float*)d_in[7];
  const float* bih1 = (const float*)d_in[8];
  const float* bhh1 = (const float*)d_in[9];
  const float* Wih2 = (const float*)d_in[10];
  const float* Whh2 = (const float*)d_in[11];
  const float* bih2 = (const float*)d_in[12];
  const float* bhh2 = (const float*)d_in[13];
  const float* Wlin = (const float*)d_in[14];
  const float* blin = (const float*)d_in[15];

  float*    xg0 = (float*)d_ws;                           // 1024*4096 f32 (16 MB)
  uint32_t* h0p = (uint32_t*)(xg0 + (size_t)1024 * 4096); // 1024*512 dw (2 MB)
  uint32_t* h1p = h0p + (size_t)1024 * 512;               // 1024*256 dw (1 MB)
  float*    h2f = (float*)(h1p + (size_t)1024 * 256);     // 1024*256 f32 (1 MB)

  (void)hipFuncSetAttribute((const void*)pipe_k,
                            hipFuncAttributeMaxDynamicSharedMemorySize,
                            PIPE_DYN_LDS);

  // Sentinel-fill h buffers (0xFFFFFFFF = NaN / dual-bf16-NaN, never valid).
  hipMemsetAsync(h0p, 0xFF,
                 ((size_t)1024 * 512 + (size_t)1024 * 256 + (size_t)1024 * 256) * 4,
                 stream);
  xg0_k<<<1024, 512, 0, stream>>>(tokens, emb, Wih0, bih0, bhh0, xg0);
  pipe_k<<<168, 512, PIPE_DYN_LDS, stream>>>(xg0, Whh0,
                                             Wih1, Whh1, bih1, bhh1,
                                             Wih2, Whh2, bih2, bhh2,
                                             Wlin, blin, h0p, h1p, h2f, (float*)d_out);
}

// Round 9
// 3274.159 us; speedup vs baseline: 1.3389x; 1.3389x over previous
//
#include <hip/hip_runtime.h>
#include <math.h>
#include <stdint.h>

#define SLEN 1024

__device__ __forceinline__ float sigf(float x) { return 1.0f / (1.0f + __expf(-x)); }

__device__ __forceinline__ uint32_t aldu(const uint32_t* p) {
  return __hip_atomic_load(p, __ATOMIC_RELAXED, __HIP_MEMORY_SCOPE_AGENT);
}
__device__ __forceinline__ void astu(uint32_t* p, uint32_t v) {
  __hip_atomic_store(p, v, __ATOMIC_RELAXED, __HIP_MEMORY_SCOPE_AGENT);
}
__device__ __forceinline__ float aldf(const float* p) {
  return __hip_atomic_load(p, __ATOMIC_RELAXED, __HIP_MEMORY_SCOPE_AGENT);
}
__device__ __forceinline__ void astf(float* p, float v) {
  __hip_atomic_store(p, v, __ATOMIC_RELAXED, __HIP_MEMORY_SCOPE_AGENT);
}
__device__ __forceinline__ bool sentu(uint32_t v) { return v == 0xFFFFFFFFu; }
__device__ __forceinline__ bool sentf(float f) { return __float_as_uint(f) == 0xFFFFFFFFu; }
// bf16-pair pack/unpack (RNE). Sentinel 0xFFFFFFFF = dual-NaN, unreachable
// from finite h. One dword covers 2 units -> single-transaction visibility.
__device__ __forceinline__ float blo(uint32_t d) { return __uint_as_float(d << 16); }
__device__ __forceinline__ float bhi(uint32_t d) { return __uint_as_float(d & 0xFFFF0000u); }
__device__ __forceinline__ uint32_t bpack(float lo, float hi) {
  uint32_t a = __float_as_uint(lo), b = __float_as_uint(hi);
  a = (a + 0x7FFFu + ((a >> 16) & 1u)) >> 16;
  b = (b + 0x7FFFu + ((b >> 16) & 1u)) & 0xFFFF0000u;
  return b | a;
}

// In-loop register pin (R5-proven safe for <=64 floats/thread).
__device__ __forceinline__ void pin4(float4& v) {
  asm volatile("" : "+v"(v.x), "+v"(v.y), "+v"(v.z), "+v"(v.w));
}
#define DOT4(acc, wv, iv)                                                  \
  acc += (wv).x * (iv).x + (wv).y * (iv).y + (wv).z * (iv).z + (wv).w * (iv).w

// ---------------------------------------------------------------------------
// xg0_k: xg0[t][u][0..3] = Wih0 rows . emb[tok_t] + bih0 + bhh0 (t-parallel)
// ---------------------------------------------------------------------------
__global__ __launch_bounds__(512, 2) void xg0_k(const int* __restrict__ tokens,
                                                const float* __restrict__ emb,
                                                const float* __restrict__ Wih0,
                                                const float* __restrict__ bih0,
                                                const float* __restrict__ bhh0,
                                                float* __restrict__ xg0) {
  const int tid = threadIdx.x, c = tid & 63, w = tid >> 6;
  const int ublk = blockIdx.x & 127;
  const int tph  = blockIdx.x >> 7;
  const int u = ublk * 8 + w;
  const float4* emb4 = (const float4*)emb;
  float4 wr[4][2];
  float bb[4];
  #pragma unroll
  for (int g = 0; g < 4; ++g) {
    const size_t row = (size_t)g * 1024 + u;
    const float4* w4 = (const float4*)(Wih0 + row * 512);
    wr[g][0] = w4[2 * c];
    wr[g][1] = w4[2 * c + 1];
    bb[g] = bih0[row] + bhh0[row];
  }
  float4* xg4 = (float4*)xg0;
  for (int t = tph; t < SLEN; t += 8) {
    const int tok = tokens[t * 64 + 63];
    const float4 e0 = emb4[(size_t)tok * 128 + 2 * c];
    const float4 e1 = emb4[(size_t)tok * 128 + 2 * c + 1];
    float a[4] = {0.f, 0.f, 0.f, 0.f};
    #pragma unroll
    for (int g = 0; g < 4; ++g) { DOT4(a[g], wr[g][0], e0); DOT4(a[g], wr[g][1], e1); }
    #pragma unroll
    for (int off = 32; off > 0; off >>= 1)
      #pragma unroll
      for (int g = 0; g < 4; ++g) a[g] += __shfl_xor(a[g], off);
    if (c == 0)
      xg4[(size_t)t * 1024 + u] =
          make_float4(a[0] + bb[0], a[1] + bb[1], a[2] + bb[2], a[3] + bb[3]);
  }
}

// ---------------------------------------------------------------------------
// L0 (R6 structure): 128 blocks x 8 units; wave w owns unit u0+w, 64 weight
// floats/thread all register-resident. ALL threads poll in parallel: thread
// tid polls 1 packed dword of h0[t-1] (2 units), unpacks into in_f.
// xg load issued BEFORE the poll (latency overlapped). 2 barriers/step.
// h store: tid<4 -> one 16B packed transaction for the block's 8 units.
// ---------------------------------------------------------------------------
__device__ void l0_role(int blk, char* blob, const float* __restrict__ Whh,
                        const float* __restrict__ xg0, uint32_t* __restrict__ h0p) {
  float* in_f = (float*)blob;                  // 1024 f32
  float* hg   = in_f + 1024;                   // 8 f32
  const int tid = threadIdx.x, c = tid & 63, w = tid >> 6;
  const int u0 = blk * 8, u = u0 + w;

  float4 wreg[4][4];
  #pragma unroll
  for (int g = 0; g < 4; ++g) {
    const float4* r4 = (const float4*)Whh + ((size_t)g * 1024 + u) * 256;
    #pragma unroll
    for (int s = 0; s < 4; ++s) wreg[g][s] = r4[s * 64 + c];
  }
  const float4* xg4 = (const float4*)xg0;
  float cst = 0.f;

  for (int t = 0; t < SLEN; ++t) {
    #pragma unroll
    for (int g = 0; g < 4; ++g)
      #pragma unroll
      for (int s = 0; s < 4; ++s) pin4(wreg[g][s]);

    float4 xgv = make_float4(0.f, 0.f, 0.f, 0.f);
    if (c == 0) xgv = xg4[(size_t)t * 1024 + u];   // issued before poll

    uint32_t hv = 0;
    if (t > 0) {
      const uint32_t* hp = h0p + (size_t)(t - 1) * 512 + tid;
      do { hv = aldu(hp); } while (sentu(hv));
      ((float2*)in_f)[tid] = make_float2(blo(hv), bhi(hv));
    } else {
      ((float2*)in_f)[tid] = make_float2(0.f, 0.f);
    }
    __syncthreads();                             // barrier 1: in_f staged

    float a[4] = {0.f, 0.f, 0.f, 0.f};
    const float4* iv4 = (const float4*)in_f;
    #pragma unroll
    for (int s = 0; s < 4; ++s) {
      const float4 iv = iv4[s * 64 + c];
      #pragma unroll
      for (int g = 0; g < 4; ++g) DOT4(a[g], wreg[g][s], iv);
    }
    #pragma unroll
    for (int off = 32; off > 0; off >>= 1)
      #pragma unroll
      for (int g = 0; g < 4; ++g) a[g] += __shfl_xor(a[g], off);

    if (c == 0) {
      const float I = sigf(a[0] + xgv.x);
      const float F = sigf(a[1] + xgv.y);
      const float G = tanhf(a[2] + xgv.z);
      const float O = sigf(a[3] + xgv.w);
      cst = F * cst + I * G;
      hg[w] = O * tanhf(cst);
    }
    __syncthreads();                             // barrier 2: hg ready
    if (tid < 4)
      astu(h0p + (size_t)t * 512 + blk * 4 + tid, bpack(hg[2 * tid], hg[2 * tid + 1]));
  }
}

// ---------------------------------------------------------------------------
// Generic role (L1/L2), R6 structure: wave owns 1 unit; RSLOTS weight slots
// in regs, SLOTS-RSLOTS in LDS. ALL threads poll in parallel (packed input,
// own h packed or f32 per PACK_OUT). Store covers the block's 8 units.
// ---------------------------------------------------------------------------
template<int HOUT, int EIN, int RSLOTS, bool PACK_OUT>
__device__ void lstm_role(int ublk, char* blob,
                          const float* __restrict__ Wih, const float* __restrict__ Whh,
                          const float* __restrict__ bih, const float* __restrict__ bhh,
                          const uint32_t* __restrict__ inp,
                          uint32_t* __restrict__ houtp, float* __restrict__ houtf) {
  constexpr int C = EIN + HOUT;
  constexpr int SLOTS = C / 256;
  constexpr int LSLOTS = SLOTS - RSLOTS;
  constexpr int XQ = EIN / 4;
  constexpr int IND = EIN / 2;                 // packed input dwords per row
  constexpr int OND = HOUT / 2;                // packed own dwords per row

  float4* wlds4 = (float4*)blob;
  float*  in_f  = (float*)(blob + (size_t)LSLOTS * 32 * 64 * 16);
  float*  hg    = in_f + C;

  const int tid = threadIdx.x, c = tid & 63, w = tid >> 6;
  const int u0 = ublk * 8, u = u0 + w;

  for (int k = tid; k < LSLOTS * 32 * 64; k += 512) {
    const int cc = k & 63, rr = k >> 6, r = rr & 31, sl = rr >> 5;
    const int g = r & 3, wu = r >> 2;
    const size_t grow = (size_t)g * HOUT + (size_t)(u0 + wu);
    const float4* wih4 = (const float4*)(Wih + grow * EIN);
    const float4* whh4 = (const float4*)(Whh + grow * HOUT);
    const int c4 = (RSLOTS + sl) * 64 + cc;
    wlds4[k] = (c4 < XQ) ? wih4[c4] : whh4[c4 - XQ];
  }
  float4 wreg[4][RSLOTS];
  #pragma unroll
  for (int g = 0; g < 4; ++g) {
    const size_t grow = (size_t)g * HOUT + (size_t)u;
    const float4* wih4 = (const float4*)(Wih + grow * EIN);
    const float4* whh4 = (const float4*)(Whh + grow * HOUT);
    #pragma unroll
    for (int s = 0; s < RSLOTS; ++s) {
      const int c4 = s * 64 + c;
      wreg[g][s] = (c4 < XQ) ? wih4[c4] : whh4[c4 - XQ];
    }
  }
  float bg[4] = {0.f, 0.f, 0.f, 0.f};
  float cst = 0.f;
  if (c == 0) {
    #pragma unroll
    for (int g = 0; g < 4; ++g) bg[g] = bih[g * HOUT + u] + bhh[g * HOUT + u];
  }
  __syncthreads();                             // weights staged

  for (int t = 0; t < SLEN; ++t) {
    #pragma unroll
    for (int g = 0; g < 4; ++g)
      #pragma unroll
      for (int s = 0; s < RSLOTS; ++s) pin4(wreg[g][s]);

    // ---- parallel poll: input (packed) + own h[t-1] ----
    {
      uint32_t av = 0, bu = 0;
      float bf = 0.f;
      const bool ain = (tid < IND);
      const bool bin = PACK_OUT ? (tid < OND) : (tid < HOUT);
      for (;;) {
        bool ok = true;
        if (ain) { av = aldu(inp + (size_t)t * IND + tid); ok &= !sentu(av); }
        if (t > 0 && bin) {
          if constexpr (PACK_OUT) {
            bu = aldu(houtp + (size_t)(t - 1) * OND + tid);
            ok &= !sentu(bu);
          } else {
            bf = aldf(houtf + (size_t)(t - 1) * HOUT + tid);
            ok &= !sentf(bf);
          }
        }
        if (ok) break;
      }
      if (ain) ((float2*)in_f)[tid] = make_float2(blo(av), bhi(av));
      if (bin) {
        if constexpr (PACK_OUT) {
          ((float2*)(in_f + EIN))[tid] =
              (t > 0) ? make_float2(blo(bu), bhi(bu)) : make_float2(0.f, 0.f);
        } else {
          in_f[EIN + tid] = (t > 0) ? bf : 0.f;
        }
      }
    }
    __syncthreads();                             // barrier 1

    float a[4] = {0.f, 0.f, 0.f, 0.f};
    const float4* iv4 = (const float4*)in_f;
    #pragma unroll
    for (int s = 0; s < RSLOTS; ++s) {
      const float4 iv = iv4[s * 64 + c];
      #pragma unroll
      for (int g = 0; g < 4; ++g) DOT4(a[g], wreg[g][s], iv);
    }
    #pragma unroll
    for (int sl = 0; sl < LSLOTS; ++sl) {
      const float4 iv = iv4[(RSLOTS + sl) * 64 + c];
      #pragma unroll
      for (int g = 0; g < 4; ++g) {
        const float4 wv = wlds4[((sl * 32) + (w * 4 + g)) * 64 + c];
        DOT4(a[g], wv, iv);
      }
    }
    #pragma unroll
    for (int off = 32; off > 0; off >>= 1)
      #pragma unroll
      for (int g = 0; g < 4; ++g) a[g] += __shfl_xor(a[g], off);

    if (c == 0) {
      const float I = sigf(a[0] + bg[0]);
      const float F = sigf(a[1] + bg[1]);
      const float G = tanhf(a[2] + bg[2]);
      const float O = sigf(a[3] + bg[3]);
      cst = F * cst + I * G;
      hg[w] = O * tanhf(cst);
    }
    __syncthreads();                             // barrier 2
    if constexpr (PACK_OUT) {                    // 8 units -> 4 dwords, 16B
      if (tid < 4)
        astu(houtp + (size_t)t * OND + ublk * 4 + tid,
             bpack(hg[2 * tid], hg[2 * tid + 1]));
    } else {                                     // 8 units -> 8 f32, 32B
      if (tid < 8)
        astf(houtf + (size_t)t * HOUT + ublk * 8 + tid, hg[tid]);
    }
  }
}

// out[t,:] = h2f[t,:] @ Wlin.T + blin; 8 blocks, t strided by 8
__device__ void final_role(int fb, char* blob, const float* __restrict__ h2f,
                           const float* __restrict__ Wlin, const float* __restrict__ blin,
                           float* __restrict__ out) {
  float* red = (float*)blob;                   // 28 f32
  const int tid = threadIdx.x;
  float wl[7];
  #pragma unroll
  for (int o = 0; o < 7; ++o) wl[o] = 0.f;
  if (tid < 256) {
    #pragma unroll
    for (int o = 0; o < 7; ++o) wl[o] = Wlin[o * 256 + tid];
  }
  for (int t = fb; t < SLEN; t += 8) {
    float h = 0.f;
    if (tid < 256) {
      h = aldf(h2f + (size_t)t * 256 + tid);
      while (sentf(h)) h = aldf(h2f + (size_t)t * 256 + tid);
    }
    float p[7];
    #pragma unroll
    for (int o = 0; o < 7; ++o) p[o] = h * wl[o];
    #pragma unroll
    for (int off = 32; off > 0; off >>= 1) {
      #pragma unroll
      for (int o = 0; o < 7; ++o) p[o] += __shfl_xor(p[o], off);
    }
    const int w = tid >> 6;
    if (w < 4 && (tid & 63) == 0) {
      #pragma unroll
      for (int o = 0; o < 7; ++o) red[w * 7 + o] = p[o];
    }
    __syncthreads();
    if (tid == 0) {
      #pragma unroll
      for (int o = 0; o < 7; ++o)
        out[t * 7 + o] = red[0 + o] + red[7 + o] + red[14 + o] + red[21 + o] + blin[o];
    }
    __syncthreads();
  }
}

// Max LDS user = L1: 3*32*64*16 (96KB weights) + 1536*4 (in_f) + 32 (hg)
#define PIPE_DYN_LDS 104480

__global__ __attribute__((amdgpu_flat_work_group_size(512, 512),
                          amdgpu_waves_per_eu(2, 2))) void pipe_k(
    const float* __restrict__ xg0, const float* __restrict__ Whh0,
    const float* __restrict__ Wih1, const float* __restrict__ Whh1,
    const float* __restrict__ bih1, const float* __restrict__ bhh1,
    const float* __restrict__ Wih2, const float* __restrict__ Whh2,
    const float* __restrict__ bih2, const float* __restrict__ bhh2,
    const float* __restrict__ Wlin, const float* __restrict__ blin,
    uint32_t* __restrict__ h0p, uint32_t* __restrict__ h1p, float* __restrict__ h2f,
    float* __restrict__ out) {
  extern __shared__ __align__(16) char blob[];
  const int b = blockIdx.x;
  if (b < 128) {
    l0_role(b, blob, Whh0, xg0, h0p);
  } else if (b < 192) {
    lstm_role<512, 1024, 3, true>(b - 128, blob, Wih1, Whh1, bih1, bhh1, h0p, h1p, nullptr);
  } else if (b < 224) {
    lstm_role<256, 512, 3, false>(b - 192, blob, Wih2, Whh2, bih2, bhh2, h1p, nullptr, h2f);
  } else {
    final_role(b - 224, blob, h2f, Wlin, blin, out);
  }
}

extern "C" void kernel_launch(void* const* d_in, const int* in_sizes, int n_in,
                              void* d_out, int out_size, void* d_ws, size_t ws_size,
                              hipStream_t stream) {
  const int*   tokens = (const int*)  d_in[0];
  const float* emb  = (const float*)d_in[1];
  const float* Wih0 = (const float*)d_in[2];
  const float* Whh0 = (const float*)d_in[3];
  const float* bih0 = (const float*)d_in[4];
  const float* bhh0 = (const float*)d_in[5];
  const float* Wih1 = (const float*)d_in[6];
  const float* Whh1 = (const float*)d_in[7];
  const float* bih1 = (const float*)d_in[8];
  const float* bhh1 = (const float*)d_in[9];
  const float* Wih2 = (const float*)d_in[10];
  const float* Whh2 = (const float*)d_in[11];
  const float* bih2 = (const float*)d_in[12];
  const float* bhh2 = (const float*)d_in[13];
  const float* Wlin = (const float*)d_in[14];
  const float* blin = (const float*)d_in[15];

  float*    xg0 = (float*)d_ws;                           // 1024*4096 f32 (16 MB)
  uint32_t* h0p = (uint32_t*)(xg0 + (size_t)1024 * 4096); // 1024*512 dw (2 MB)
  uint32_t* h1p = h0p + (size_t)1024 * 512;               // 1024*256 dw (1 MB)
  float*    h2f = (float*)(h1p + (size_t)1024 * 256);     // 1024*256 f32 (1 MB)

  (void)hipFuncSetAttribute((const void*)pipe_k,
                            hipFuncAttributeMaxDynamicSharedMemorySize,
                            PIPE_DYN_LDS);

  // Sentinel-fill h buffers (0xFFFFFFFF = NaN / dual-bf16-NaN, never valid).
  hipMemsetAsync(h0p, 0xFF,
                 ((size_t)1024 * 512 + (size_t)1024 * 256 + (size_t)1024 * 256) * 4,
                 stream);
  xg0_k<<<1024, 512, 0, stream>>>(tokens, emb, Wih0, bih0, bhh0, xg0);
  pipe_k<<<232, 512, PIPE_DYN_LDS, stream>>>(xg0, Whh0,
                                             Wih1, Whh1, bih1, bhh1,
                                             Wih2, Whh2, bih2, bhh2,
                                             Wlin, blin, h0p, h1p, h2f, (float*)d_out);
}